// Round 8
// baseline (91.699 us; speedup 1.0000x reference)
//
#include <hip/hip_runtime.h>

#define N_TEX 65536
#define C 16
#define U 4194304
#define ILP 4
#define WPAR_REP 3
#define WTEX_REP 6

typedef float    f32x4 __attribute__((ext_vector_type(4)));
typedef int      i32x4 __attribute__((ext_vector_type(4)));
typedef _Float16 f16x4 __attribute__((ext_vector_type(4)));

// ---------------------------------------------------------------------------
// Convert fp32 texture (4 MiB) -> fp16 (2 MiB) in d_ws.
// ---------------------------------------------------------------------------
__global__ __launch_bounds__(256) void convert_kernel(
    const f32x4* __restrict__ in, f16x4* __restrict__ out16)
{
    const int i = blockIdx.x * 256 + threadIdx.x;
    f32x4 v = __builtin_nontemporal_load(&in[i]);
    f16x4 h;
    h.x = (_Float16)v.x; h.y = (_Float16)v.y;
    h.z = (_Float16)v.z; h.w = (_Float16)v.w;
    out16[i] = h;
}

// ---------------------------------------------------------------------------
// Warm kernel with REUSE PROMOTION. 2,048 blocks, XCD-aware (XCD = b%8).
// Theory: L2 replacement favors lines with multiple touches (RRIP-like);
// single-touch warm lines get cycled out by the sampler's 256 MiB store
// stream, which is why R6/R7 warming only bought 14 us. D1 (16 touches)
// bought 54 us. So touch param 3x and texture 6x, rotating addresses per rep
// (bijective within the chunk) so each line really is re-referenced.
//   - param: block b covers the slices of the 8 sampler blocks s == b (mod 8)
//     in its range (sampler block s reads f32x4 units s*16+m+k*262144).
//   - texture: chunk c = b>>3 (8 KiB); per XCD its 256 blocks cover the full
//     2 MiB texture -> every XCD's L2 holds a complete, promoted copy.
// ---------------------------------------------------------------------------
__global__ __launch_bounds__(256) void warm_kernel(
    const i32x4* __restrict__ texv, const f32x4* __restrict__ paramv)
{
    const int b = blockIdx.x;   // 0..2047
    const int t = threadIdx.x;

    // --- param: 8 KiB per block, 3 touches each line
    const int i  = t >> 5;                  // which of 8 sampler blocks
    const int g  = t & 31;
    const int s  = (b & 7) + 8 * ((b >> 3) * 8 + i);
    const int m  = g & 15;
    const int k0 = g >> 4;                  // {0,1}
#pragma unroll
    for (int r = 0; r < WPAR_REP; ++r) {
        const int mm = (m + r * 5) & 15;    // bijective rotation in [0,16)
        f32x4 p0 = paramv[s * 16 + mm + k0 * 262144];
        f32x4 p1 = paramv[s * 16 + mm + (k0 + 2) * 262144];
        asm volatile("" :: "v"(p0), "v"(p1));
    }

    // --- texture: 8 KiB chunk (512 x 16 B units), 6 touches each line
    const int cbase = (b >> 3) * 512;
#pragma unroll
    for (int r = 0; r < WTEX_REP; ++r) {
        const int u0 = ((t + r * 37) & 255) * 2;  // bijective over t per rep
        i32x4 t0 = texv[cbase + u0];
        i32x4 t1 = texv[cbase + u0 + 1];
        asm volatile("" :: "v"(t0), "v"(t1));
    }
}

// ---------------------------------------------------------------------------
// Sampler (unchanged): 4 lanes per sample, fp16 texture, ILP=4,
// nontemporal param loads + output stores.
// ---------------------------------------------------------------------------
__global__ __launch_bounds__(256) void sampler1d_kernel(
    const f16x4* __restrict__ tex16, const float* __restrict__ param,
    f32x4* __restrict__ out)
{
    const int NT  = (U * 4) / ILP;
    const int tid = blockIdx.x * 256 + threadIdx.x;
    const int q   = tid & 3;

    float p[ILP];
#pragma unroll
    for (int k = 0; k < ILP; ++k)
        p[k] = __builtin_nontemporal_load(&param[(tid + k * NT) >> 2]);

    float w[ILP];
    f16x4 a[ILP], b[ILP];
#pragma unroll
    for (int k = 0; k < ILP; ++k) {
        const float t = p[k] * (float)(N_TEX - 1);
        float f = floorf(t);
        f = fminf(fmaxf(f, 0.0f), (float)(N_TEX - 1));
        const int i0 = (int)f;
        const int i1 = min(i0 + 1, N_TEX - 1);
        w[k] = t - f;
        a[k] = tex16[i0 * 4 + q];
        b[k] = tex16[i1 * 4 + q];
    }

#pragma unroll
    for (int k = 0; k < ILP; ++k) {
        const float wk = w[k], iw = 1.0f - wk;
        f32x4 r;
        r.x = (float)a[k].x * iw + (float)b[k].x * wk;
        r.y = (float)a[k].y * iw + (float)b[k].y * wk;
        r.z = (float)a[k].z * iw + (float)b[k].z * wk;
        r.w = (float)a[k].w * iw + (float)b[k].w * wk;
        __builtin_nontemporal_store(r, &out[tid + k * NT]);
    }
}

extern "C" void kernel_launch(void* const* d_in, const int* in_sizes, int n_in,
                              void* d_out, int out_size, void* d_ws, size_t ws_size,
                              hipStream_t stream) {
    const f32x4* tex32 = (const f32x4*)d_in[0];
    const float* param = (const float*)d_in[1];
    f32x4*       out   = (f32x4*)d_out;
    f16x4*       tex16 = (f16x4*)d_ws;     // 2 MiB scratch

    const int total_thr = (U * 4) / ILP;   // 4,194,304 -> 16,384 blocks

    convert_kernel<<<(N_TEX * C / 4) / 256, 256, 0, stream>>>(tex32, tex16);
    warm_kernel<<<2048, 256, 0, stream>>>((const i32x4*)tex16, (const f32x4*)param);
    sampler1d_kernel<<<total_thr / 256, 256, 0, stream>>>(tex16, param, out);
}